// Round 10
// baseline (1228.543 us; speedup 1.0000x reference)
//
#include <hip/hip_runtime.h>

#define NN 100000      // N_NODES
#define NE 1000000     // N_EDGES
#define HID 75
#define SP 80          // padded feature stride (fp32 h buffers)
#define OUTF 64
#define BN_EPS 1e-5f
#define KP 104         // LDS k-stride in bf16 (96 used; 16B-aligned, ~2-way banks)

#define SCAN_ELEMS 1024
#define SCAN_NBLK ((NN + SCAN_ELEMS - 1) / SCAN_ELEMS)   // 98

typedef short bf16x8 __attribute__((ext_vector_type(8)));
typedef float f32x4  __attribute__((ext_vector_type(4)));

// bf16 helpers
__device__ __forceinline__ ushort f2bf(float f) {
    unsigned u = __float_as_uint(f);
    u += 0x7FFF + ((u >> 16) & 1);          // round-to-nearest-even
    return (ushort)(u >> 16);
}
__device__ __forceinline__ float bf_lo(unsigned u) { return __uint_as_float(u << 16); }
__device__ __forceinline__ float bf_hi(unsigned u) { return __uint_as_float(u & 0xFFFF0000u); }

// ---------------- CSR build ----------------
__global__ void hist_kernel(const int* __restrict__ dst, int* __restrict__ hist, int E) {
    int e = blockIdx.x * blockDim.x + threadIdx.x;
    if (e < E) atomicAdd(&hist[dst[e]], 1);
}

__global__ void dinv_kernel(const int* __restrict__ hist, float* __restrict__ dinv, int n) {
    int i = blockIdx.x * blockDim.x + threadIdx.x;
    if (i < n) dinv[i] = rsqrtf((float)hist[i] + 1.0f);   // +1 self-loop
}

__global__ void scan_pass1(const int* __restrict__ hist, int* __restrict__ bsum) {
    __shared__ int sdata[256];
    int base = blockIdx.x * SCAN_ELEMS;
    int t = threadIdx.x;
    int s = 0;
    #pragma unroll
    for (int k = 0; k < 4; ++k) {
        int i = base + t * 4 + k;
        if (i < NN) s += hist[i];
    }
    sdata[t] = s;
    __syncthreads();
    for (int off = 128; off > 0; off >>= 1) {
        if (t < off) sdata[t] += sdata[t + off];
        __syncthreads();
    }
    if (t == 0) bsum[blockIdx.x] = sdata[0];
}

__global__ void scan_pass2(int* __restrict__ bsum, int* __restrict__ row_ptr, int nblk) {
    if (threadIdx.x == 0) {
        int acc = 0;
        for (int i = 0; i < nblk; ++i) { int v = bsum[i]; bsum[i] = acc; acc += v; }
        row_ptr[NN] = acc;
    }
}

__global__ void scan_pass3(const int* __restrict__ hist, const int* __restrict__ bsum,
                           int* __restrict__ row_ptr) {
    __shared__ int sdata[256];
    int base = blockIdx.x * SCAN_ELEMS;
    int t = threadIdx.x;
    int v[4];
    int s = 0;
    #pragma unroll
    for (int k = 0; k < 4; ++k) {
        int i = base + t * 4 + k;
        v[k] = (i < NN) ? hist[i] : 0;
        s += v[k];
    }
    sdata[t] = s;
    __syncthreads();
    for (int off = 1; off < 256; off <<= 1) {
        int x = (t >= off) ? sdata[t - off] : 0;
        __syncthreads();
        sdata[t] += x;
        __syncthreads();
    }
    int pre = bsum[blockIdx.x] + sdata[t] - s;
    #pragma unroll
    for (int k = 0; k < 4; ++k) {
        int i = base + t * 4 + k;
        if (i < NN) { row_ptr[i] = pre; pre += v[k]; }
    }
}

__global__ void csr_fill(const int* __restrict__ src, const int* __restrict__ dst,
                         const int* __restrict__ row_ptr, int* __restrict__ cnt,
                         int* __restrict__ col, int E) {
    int e = blockIdx.x * blockDim.x + threadIdx.x;
    if (e >= E) return;
    int d = dst[e];
    int slot = row_ptr[d] + atomicAdd(&cnt[d], 1);
    col[slot] = src[e];
}

// ---------------- degree-sorted permutation (equal-degree blocks -> cheap barriers) ----------------
__global__ void deg_hist_kernel(const int* __restrict__ hist, int* __restrict__ dh) {
    __shared__ int lh[64];
    if (threadIdx.x < 64) lh[threadIdx.x] = 0;
    __syncthreads();
    int i = blockIdx.x * 256 + threadIdx.x;
    if (i < NN) atomicAdd(&lh[min(hist[i], 63)], 1);
    __syncthreads();
    if (threadIdx.x < 64 && lh[threadIdx.x]) atomicAdd(&dh[threadIdx.x], lh[threadIdx.x]);
}

__global__ void deg_scan_kernel(const int* __restrict__ dh, int* __restrict__ doff) {
    if (threadIdx.x == 0) {
        int acc = 0;
        for (int d = 0; d < 64; ++d) { doff[d] = acc; acc += dh[d]; }
    }
}

__global__ void perm_fill_kernel(const int* __restrict__ hist, int* __restrict__ doff,
                                 int* __restrict__ perm) {
    __shared__ int lcnt[64];
    __shared__ int gbase[64];
    if (threadIdx.x < 64) lcnt[threadIdx.x] = 0;
    __syncthreads();
    int i = blockIdx.x * 256 + threadIdx.x;
    int d = 0, lrank = 0;
    bool act = (i < NN);
    if (act) { d = min(hist[i], 63); lrank = atomicAdd(&lcnt[d], 1); }
    __syncthreads();
    if (threadIdx.x < 64) {
        int c = lcnt[threadIdx.x];
        gbase[threadIdx.x] = c ? atomicAdd(&doff[threadIdx.x], c) : 0;
    }
    __syncthreads();
    if (act) perm[gbase[d] + lrank] = i;
}

// ---------------- embedding gather ----------------
__global__ void embed_kernel(const int* __restrict__ x, const float* __restrict__ emb,
                             float* __restrict__ h) {
    int t = blockIdx.x * blockDim.x + threadIdx.x;
    if (t >= NN * SP) return;
    int node = t / SP, f = t % SP;
    h[t] = (f < HID) ? emb[x[node] * HID + f] : 0.0f;
}

// ---------------- MFMA GEMM: outb[n] = bf16( dinv[n] * (BNReLU(h[n]) @ W) ) ----------------
template<int J, bool BNRELU>
__global__ __launch_bounds__(256, 2)
void gemm_mfma(const float* __restrict__ h, const float* __restrict__ W,
               const float* __restrict__ ab, const float* __restrict__ dinv,
               ushort* __restrict__ outb) {
    constexpr int NT = (J + 15) / 16;   // 5 (J=75) or 4 (J=64)
    constexpr int JP = NT * 16;         // 80 or 64
    constexpr int OS = JP;
    __shared__ ushort Wl[JP * KP];
    __shared__ ushort Hl[64 * KP];
    int tl = threadIdx.x;
    int rbase = blockIdx.x * 64;
    for (int idx = tl; idx < 96 * JP; idx += 256) {
        int k = idx / JP, n = idx % JP;
        float v = (k < HID && n < J) ? W[k * J + n] : 0.0f;
        Wl[n * KP + k] = f2bf(v);
    }
    for (int idx = tl; idx < 64 * 20; idx += 256) {
        int r = idx / 20, c = idx % 20;
        int row = rbase + r; if (row >= NN) row = NN - 1;
        float4 v = reinterpret_cast<const float4*>(h + (size_t)row * SP)[c];
        if (BNRELU) {
            float4 a4 = reinterpret_cast<const float4*>(ab)[c];
            float4 c4 = reinterpret_cast<const float4*>(ab + SP)[c];
            v.x = fmaxf(fmaf(v.x, a4.x, c4.x), 0.f);
            v.y = fmaxf(fmaf(v.y, a4.y, c4.y), 0.f);
            v.z = fmaxf(fmaf(v.z, a4.z, c4.z), 0.f);
            v.w = fmaxf(fmaf(v.w, a4.w, c4.w), 0.f);
        }
        ushort4 u;
        u.x = f2bf(v.x); u.y = f2bf(v.y); u.z = f2bf(v.z); u.w = f2bf(v.w);
        *reinterpret_cast<ushort4*>(&Hl[r * KP + c * 4]) = u;
    }
    for (int idx = tl; idx < 64 * 16; idx += 256) {
        int r = idx / 16, k = 80 + (idx % 16);
        Hl[r * KP + k] = 0;
    }
    __syncthreads();
    int w = tl >> 6;
    int l = tl & 63;
    int cq = l & 15;
    int q  = l >> 4;
    f32x4 acc[NT] = {};
    #pragma unroll
    for (int ks = 0; ks < 3; ++ks) {
        int k0 = ks * 32 + q * 8;
        bf16x8 a = *reinterpret_cast<const bf16x8*>(&Hl[(w * 16 + cq) * KP + k0]);
        #pragma unroll
        for (int t = 0; t < NT; ++t) {
            bf16x8 b = *reinterpret_cast<const bf16x8*>(&Wl[(t * 16 + cq) * KP + k0]);
            acc[t] = __builtin_amdgcn_mfma_f32_16x16x32_bf16(a, b, acc[t], 0, 0, 0);
        }
    }
    int r0 = rbase + w * 16 + q * 4;
    #pragma unroll
    for (int r = 0; r < 4; ++r) {
        int grow = r0 + r;
        if (grow < NN) {
            float d = dinv[grow];
            ushort* orow = outb + (size_t)grow * OS;
            #pragma unroll
            for (int t = 0; t < NT; ++t)
                orow[t * 16 + cq] = f2bf(acc[t][r] * d);
        }
    }
}

// Fused final GEMM: J=128 (W_mu || W_ls), outb stride 128.
__global__ __launch_bounds__(256, 2)
void gemm_mfma_dual(const float* __restrict__ h, const float* __restrict__ Wmu,
                    const float* __restrict__ Wls, const float* __restrict__ ab,
                    const float* __restrict__ dinv, ushort* __restrict__ outb) {
    constexpr int NT = 8;
    constexpr int JP = 128;
    __shared__ ushort Wl[JP * KP];   // 26.6 KB
    __shared__ ushort Hl[64 * KP];   // 13.3 KB
    int tl = threadIdx.x;
    int rbase = blockIdx.x * 64;
    for (int idx = tl; idx < 96 * JP; idx += 256) {
        int k = idx / JP, n = idx % JP;
        float v = 0.f;
        if (k < HID) v = (n < 64) ? Wmu[k * 64 + n] : Wls[k * 64 + (n - 64)];
        Wl[n * KP + k] = f2bf(v);
    }
    for (int idx = tl; idx < 64 * 20; idx += 256) {
        int r = idx / 20, c = idx % 20;
        int row = rbase + r; if (row >= NN) row = NN - 1;
        float4 v = reinterpret_cast<const float4*>(h + (size_t)row * SP)[c];
        float4 a4 = reinterpret_cast<const float4*>(ab)[c];
        float4 c4 = reinterpret_cast<const float4*>(ab + SP)[c];
        v.x = fmaxf(fmaf(v.x, a4.x, c4.x), 0.f);
        v.y = fmaxf(fmaf(v.y, a4.y, c4.y), 0.f);
        v.z = fmaxf(fmaf(v.z, a4.z, c4.z), 0.f);
        v.w = fmaxf(fmaf(v.w, a4.w, c4.w), 0.f);
        ushort4 u;
        u.x = f2bf(v.x); u.y = f2bf(v.y); u.z = f2bf(v.z); u.w = f2bf(v.w);
        *reinterpret_cast<ushort4*>(&Hl[r * KP + c * 4]) = u;
    }
    for (int idx = tl; idx < 64 * 16; idx += 256) {
        int r = idx / 16, k = 80 + (idx % 16);
        Hl[r * KP + k] = 0;
    }
    __syncthreads();
    int w = tl >> 6;
    int l = tl & 63;
    int cq = l & 15;
    int q  = l >> 4;
    f32x4 acc[NT] = {};
    #pragma unroll
    for (int ks = 0; ks < 3; ++ks) {
        int k0 = ks * 32 + q * 8;
        bf16x8 a = *reinterpret_cast<const bf16x8*>(&Hl[(w * 16 + cq) * KP + k0]);
        #pragma unroll
        for (int t = 0; t < NT; ++t) {
            bf16x8 b = *reinterpret_cast<const bf16x8*>(&Wl[(t * 16 + cq) * KP + k0]);
            acc[t] = __builtin_amdgcn_mfma_f32_16x16x32_bf16(a, b, acc[t], 0, 0, 0);
        }
    }
    int r0 = rbase + w * 16 + q * 4;
    #pragma unroll
    for (int r = 0; r < 4; ++r) {
        int grow = r0 + r;
        if (grow < NN) {
            float d = dinv[grow];
            ushort* orow = outb + (size_t)grow * 128;
            #pragma unroll
            for (int t = 0; t < NT; ++t)
                orow[t * 16 + cq] = f2bf(acc[t][r] * d);
        }
    }
}

// ---------------- CSR gather (bf16 uint2 loads, degree-sorted rows) ----------------
#define ACCUM(W) \
    a0 += bf_lo(W.x); a1 += bf_hi(W.x); a2 += bf_lo(W.y); a3 += bf_hi(W.y);

// 20 lanes per row, 8B per lane, unroll-8 MLP, FUSED BN stats.
// Degree-sorted perm => all rows in a block have equal degree => the stats
// barrier costs ~nothing. No early return (barrier legality): act-guards.
__global__ void gather75(const int* __restrict__ row_ptr, const int* __restrict__ col,
                         const int* __restrict__ perm,
                         const uint2* __restrict__ hWb, const float* __restrict__ dinv,
                         float* __restrict__ agg, float* __restrict__ stats) {
    __shared__ float ssum[SP], ssq[SP];
    int tl = threadIdx.x;
    if (tl < SP) { ssum[tl] = 0.f; ssq[tl] = 0.f; }
    __syncthreads();
    int t = blockIdx.x * 256 + tl;
    bool act = (t < NN * 20);
    float f0 = 0.f, f1 = 0.f, f2 = 0.f, f3 = 0.f;
    int n = 0, c = 0;
    if (act) {
        n = perm[t / 20];
        c = t % 20;
        int beg = row_ptr[n], end = row_ptr[n + 1];
        uint2 v = hWb[n * 20 + c];     // self term (pre-scaled by dinv[src])
        float a0 = bf_lo(v.x), a1 = bf_hi(v.x), a2 = bf_lo(v.y), a3 = bf_hi(v.y);
        int e = beg;
        for (; e + 7 < end; e += 8) {
            int s0 = col[e],     s1 = col[e + 1], s2 = col[e + 2], s3 = col[e + 3];
            int s4 = col[e + 4], s5 = col[e + 5], s6 = col[e + 6], s7 = col[e + 7];
            uint2 w0 = hWb[s0 * 20 + c];
            uint2 w1 = hWb[s1 * 20 + c];
            uint2 w2 = hWb[s2 * 20 + c];
            uint2 w3 = hWb[s3 * 20 + c];
            uint2 w4 = hWb[s4 * 20 + c];
            uint2 w5 = hWb[s5 * 20 + c];
            uint2 w6 = hWb[s6 * 20 + c];
            uint2 w7 = hWb[s7 * 20 + c];
            ACCUM(w0) ACCUM(w1) ACCUM(w2) ACCUM(w3)
            ACCUM(w4) ACCUM(w5) ACCUM(w6) ACCUM(w7)
        }
        for (; e + 3 < end; e += 4) {
            int s0 = col[e], s1 = col[e + 1], s2 = col[e + 2], s3 = col[e + 3];
            uint2 w0 = hWb[s0 * 20 + c];
            uint2 w1 = hWb[s1 * 20 + c];
            uint2 w2 = hWb[s2 * 20 + c];
            uint2 w3 = hWb[s3 * 20 + c];
            ACCUM(w0) ACCUM(w1) ACCUM(w2) ACCUM(w3)
        }
        for (; e < end; ++e) {
            uint2 w0 = hWb[col[e] * 20 + c];
            ACCUM(w0)
        }
        float d = dinv[n];
        f0 = a0 * d; f1 = a1 * d; f2 = a2 * d; f3 = a3 * d;
        reinterpret_cast<float4*>(agg)[n * 20 + c] = make_float4(f0, f1, f2, f3);
        int fb = c * 4;
        atomicAdd(&ssum[fb + 0], f0); atomicAdd(&ssq[fb + 0], f0 * f0);
        atomicAdd(&ssum[fb + 1], f1); atomicAdd(&ssq[fb + 1], f1 * f1);
        atomicAdd(&ssum[fb + 2], f2); atomicAdd(&ssq[fb + 2], f2 * f2);
        atomicAdd(&ssum[fb + 3], f3); atomicAdd(&ssq[fb + 3], f3 * f3);
    }
    __syncthreads();
    if (tl < SP) {
        atomicAdd(&stats[tl], ssum[tl]);
        atomicAdd(&stats[SP + tl], ssq[tl]);
    }
}

// Fused mu+logstd gather: 32 lanes per row over the 128-wide dual hW.
__global__ void gather128(const int* __restrict__ row_ptr, const int* __restrict__ col,
                          const int* __restrict__ perm,
                          const uint2* __restrict__ hWb, const float* __restrict__ dinv,
                          const float* __restrict__ b_mu, const float* __restrict__ b_ls,
                          float* __restrict__ out_mu, float* __restrict__ out_ls) {
    int t = blockIdx.x * 256 + threadIdx.x;
    int n = perm[t >> 5];
    int c = t & 31;
    int beg = row_ptr[n], end = row_ptr[n + 1];
    uint2 v = hWb[n * 32 + c];
    float a0 = bf_lo(v.x), a1 = bf_hi(v.x), a2 = bf_lo(v.y), a3 = bf_hi(v.y);
    int e = beg;
    for (; e + 7 < end; e += 8) {
        int s0 = col[e],     s1 = col[e + 1], s2 = col[e + 2], s3 = col[e + 3];
        int s4 = col[e + 4], s5 = col[e + 5], s6 = col[e + 6], s7 = col[e + 7];
        uint2 w0 = hWb[s0 * 32 + c];
        uint2 w1 = hWb[s1 * 32 + c];
        uint2 w2 = hWb[s2 * 32 + c];
        uint2 w3 = hWb[s3 * 32 + c];
        uint2 w4 = hWb[s4 * 32 + c];
        uint2 w5 = hWb[s5 * 32 + c];
        uint2 w6 = hWb[s6 * 32 + c];
        uint2 w7 = hWb[s7 * 32 + c];
        ACCUM(w0) ACCUM(w1) ACCUM(w2) ACCUM(w3)
        ACCUM(w4) ACCUM(w5) ACCUM(w6) ACCUM(w7)
    }
    for (; e + 3 < end; e += 4) {
        int s0 = col[e], s1 = col[e + 1], s2 = col[e + 2], s3 = col[e + 3];
        uint2 w0 = hWb[s0 * 32 + c];
        uint2 w1 = hWb[s1 * 32 + c];
        uint2 w2 = hWb[s2 * 32 + c];
        uint2 w3 = hWb[s3 * 32 + c];
        ACCUM(w0) ACCUM(w1) ACCUM(w2) ACCUM(w3)
    }
    for (; e < end; ++e) {
        uint2 w0 = hWb[col[e] * 32 + c];
        ACCUM(w0)
    }
    float d = dinv[n];
    const float* bp = (c < 16) ? (b_mu + c * 4) : (b_ls + (c - 16) * 4);
    float* op = (c < 16) ? (out_mu + (size_t)n * 64 + c * 4)
                         : (out_ls + (size_t)n * 64 + (c - 16) * 4);
    float4 b = *reinterpret_cast<const float4*>(bp);
    *reinterpret_cast<float4*>(op) =
        make_float4(fmaf(a0, d, b.x), fmaf(a1, d, b.y), fmaf(a2, d, b.z), fmaf(a3, d, b.w));
}

__global__ void bn_finalize(const float* __restrict__ stats, const float* __restrict__ gamma,
                            const float* __restrict__ beta, float* __restrict__ ab) {
    int f = threadIdx.x;
    if (f >= SP) return;
    float a = 0.f, cc = 0.f;
    if (f < HID) {
        float mu = stats[f] * (1.0f / NN);
        float var = stats[SP + f] * (1.0f / NN) - mu * mu;
        a = gamma[f] * rsqrtf(var + BN_EPS);
        cc = beta[f] - mu * a;
    }
    ab[f] = a;
    ab[SP + f] = cc;
}

// ---------------- host ----------------
extern "C" void kernel_launch(void* const* d_in, const int* in_sizes, int n_in,
                              void* d_out, int out_size, void* d_ws, size_t ws_size,
                              hipStream_t stream) {
    const int*   x      = (const int*)d_in[0];
    const int*   ei     = (const int*)d_in[1];
    const float* emb    = (const float*)d_in[2];
    const float* Ws     = (const float*)d_in[3];
    const float* gammas = (const float*)d_in[5];
    const float* betas  = (const float*)d_in[6];
    const float* W_mu   = (const float*)d_in[7];
    const float* b_mu   = (const float*)d_in[8];
    const float* W_ls   = (const float*)d_in[9];
    const float* b_ls   = (const float*)d_in[10];
    float* out = (float*)d_out;

    const int E = in_sizes[1] / 2;
    const int* src = ei;
    const int* dst = ei + E;

    char* ws = (char*)d_ws;
    float*  dinv    = (float*) (ws + 0);            // NN floats
    float*  stats   = (float*) (ws + 400000);       // 160 floats
    float*  ab      = (float*) (ws + 400640);       // 160 floats
    int*    hist    = (int*)   (ws + 401408);       // NN ints
    int*    row_ptr = (int*)   (ws + 801408);       // NN+1 ints
    int*    cnt     = (int*)   (ws + 1201536);      // NN ints
    int*    bsum    = (int*)   (ws + 1601536);      // SCAN_NBLK ints
    int*    col     = (int*)   (ws + 1602048);      // NE ints (4 MB)
    float*  hA      = (float*) (ws + 5602048);      // NN*SP fp32 (32 MB)
    ushort* hBb     = (ushort*)(ws + 37602048);     // NN*128 bf16 max (25.6 MB)
    int*    perm    = (int*)   (ws + 63202048);     // NN ints
    int*    dh      = (int*)   (ws + 63602048);     // 64 ints
    int*    doff    = (int*)   (ws + 63602304);     // 64 ints

    // --- CSR build ---
    hipMemsetAsync(hist, 0, NN * sizeof(int), stream);
    hist_kernel<<<(E + 255) / 256, 256, 0, stream>>>(dst, hist, E);
    dinv_kernel<<<(NN + 255) / 256, 256, 0, stream>>>(hist, dinv, NN);
    scan_pass1<<<SCAN_NBLK, 256, 0, stream>>>(hist, bsum);
    scan_pass2<<<1, 64, 0, stream>>>(bsum, row_ptr, SCAN_NBLK);
    scan_pass3<<<SCAN_NBLK, 256, 0, stream>>>(hist, bsum, row_ptr);
    hipMemsetAsync(cnt, 0, NN * sizeof(int), stream);
    csr_fill<<<(E + 255) / 256, 256, 0, stream>>>(src, dst, row_ptr, cnt, col, E);

    // --- degree-sorted permutation ---
    hipMemsetAsync(dh, 0, 64 * sizeof(int), stream);
    deg_hist_kernel<<<(NN + 255) / 256, 256, 0, stream>>>(hist, dh);
    deg_scan_kernel<<<1, 64, 0, stream>>>(dh, doff);
    perm_fill_kernel<<<(NN + 255) / 256, 256, 0, stream>>>(hist, doff, perm);

    // --- h0 = emb[x] ---
    embed_kernel<<<(NN * SP + 255) / 256, 256, 0, stream>>>(x, emb, hA);

    // --- 4 GCN+BN+ReLU layers (stats fused into gather75) ---
    for (int layer = 0; layer < 4; ++layer) {
        const float* W = Ws + (size_t)layer * HID * HID;
        if (layer == 0)
            gemm_mfma<HID, false><<<(NN + 63) / 64, 256, 0, stream>>>(hA, W, ab, dinv, hBb);
        else
            gemm_mfma<HID, true><<<(NN + 63) / 64, 256, 0, stream>>>(hA, W, ab, dinv, hBb);
        hipMemsetAsync(stats, 0, 2 * SP * sizeof(float), stream);
        gather75<<<(NN * 20 + 255) / 256, 256, 0, stream>>>(row_ptr, col, perm,
                                                            (const uint2*)hBb, dinv, hA, stats);
        bn_finalize<<<1, 128, 0, stream>>>(stats, gammas + layer * HID, betas + layer * HID, ab);
    }

    // --- fused mu + logstd ---
    float* out2 = out + (size_t)NN * OUTF;
    gemm_mfma_dual<<<(NN + 63) / 64, 256, 0, stream>>>(hA, W_mu, W_ls, ab, dinv, hBb);
    gather128<<<(NN * 32) / 256, 256, 0, stream>>>(row_ptr, col, perm, (const uint2*)hBb,
                                                   dinv, b_mu, b_ls, out, out2);
}

// Round 11
// 575.994 us; speedup vs baseline: 2.1329x; 2.1329x over previous
//
#include <hip/hip_runtime.h>

#define NN 100000      // N_NODES
#define NE 1000000     // N_EDGES
#define HID 75
#define SP 80          // padded feature stride (bf16 h buffers)
#define OUTF 64
#define BN_EPS 1e-5f
#define KP 104         // LDS k-stride in bf16 (96 used; 16B-aligned, ~2-way banks)

#define SCAN_ELEMS 1024
#define SCAN_NBLK ((NN + SCAN_ELEMS - 1) / SCAN_ELEMS)   // 98

typedef short bf16x8 __attribute__((ext_vector_type(8)));
typedef float f32x4  __attribute__((ext_vector_type(4)));

// bf16 helpers
__device__ __forceinline__ ushort f2bf(float f) {
    unsigned u = __float_as_uint(f);
    u += 0x7FFF + ((u >> 16) & 1);          // round-to-nearest-even
    return (ushort)(u >> 16);
}
__device__ __forceinline__ float bf_lo(unsigned u) { return __uint_as_float(u << 16); }
__device__ __forceinline__ float bf_hi(unsigned u) { return __uint_as_float(u & 0xFFFF0000u); }

// ---------------- CSR build ----------------
__global__ void hist_kernel(const int* __restrict__ dst, int* __restrict__ hist, int E) {
    int e = blockIdx.x * blockDim.x + threadIdx.x;
    if (e < E) atomicAdd(&hist[dst[e]], 1);
}

__global__ void dinv_kernel(const int* __restrict__ hist, float* __restrict__ dinv, int n) {
    int i = blockIdx.x * blockDim.x + threadIdx.x;
    if (i < n) dinv[i] = rsqrtf((float)hist[i] + 1.0f);   // +1 self-loop
}

__global__ void scan_pass1(const int* __restrict__ hist, int* __restrict__ bsum) {
    __shared__ int sdata[256];
    int base = blockIdx.x * SCAN_ELEMS;
    int t = threadIdx.x;
    int s = 0;
    #pragma unroll
    for (int k = 0; k < 4; ++k) {
        int i = base + t * 4 + k;
        if (i < NN) s += hist[i];
    }
    sdata[t] = s;
    __syncthreads();
    for (int off = 128; off > 0; off >>= 1) {
        if (t < off) sdata[t] += sdata[t + off];
        __syncthreads();
    }
    if (t == 0) bsum[blockIdx.x] = sdata[0];
}

__global__ void scan_pass2(int* __restrict__ bsum, int* __restrict__ row_ptr, int nblk) {
    if (threadIdx.x == 0) {
        int acc = 0;
        for (int i = 0; i < nblk; ++i) { int v = bsum[i]; bsum[i] = acc; acc += v; }
        row_ptr[NN] = acc;
    }
}

__global__ void scan_pass3(const int* __restrict__ hist, const int* __restrict__ bsum,
                           int* __restrict__ row_ptr) {
    __shared__ int sdata[256];
    int base = blockIdx.x * SCAN_ELEMS;
    int t = threadIdx.x;
    int v[4];
    int s = 0;
    #pragma unroll
    for (int k = 0; k < 4; ++k) {
        int i = base + t * 4 + k;
        v[k] = (i < NN) ? hist[i] : 0;
        s += v[k];
    }
    sdata[t] = s;
    __syncthreads();
    for (int off = 1; off < 256; off <<= 1) {
        int x = (t >= off) ? sdata[t - off] : 0;
        __syncthreads();
        sdata[t] += x;
        __syncthreads();
    }
    int pre = bsum[blockIdx.x] + sdata[t] - s;
    #pragma unroll
    for (int k = 0; k < 4; ++k) {
        int i = base + t * 4 + k;
        if (i < NN) { row_ptr[i] = pre; pre += v[k]; }
    }
}

__global__ void csr_fill(const int* __restrict__ src, const int* __restrict__ dst,
                         const int* __restrict__ row_ptr, int* __restrict__ cnt,
                         int* __restrict__ col, int E) {
    int e = blockIdx.x * blockDim.x + threadIdx.x;
    if (e >= E) return;
    int d = dst[e];
    int slot = row_ptr[d] + atomicAdd(&cnt[d], 1);
    col[slot] = src[e];
}

// ---------------- embedding gather (bf16 out) ----------------
__global__ void embed_kernel(const int* __restrict__ x, const float* __restrict__ emb,
                             ushort* __restrict__ h) {
    int t = blockIdx.x * blockDim.x + threadIdx.x;
    if (t >= NN * SP) return;
    int node = t / SP, f = t % SP;
    h[t] = (f < HID) ? f2bf(emb[x[node] * HID + f]) : (ushort)0;
}

// ---------------- MFMA GEMM: outb[n] = bf16( dinv[n] * (BNReLU(h[n]) @ W) ) ----------------
// h is bf16 [NN][80]. W staged transposed [n][k] bf16 in LDS; H staged [64][KP] bf16
// with BN+ReLU fused at staging (fp32 math on unpacked bf16).
template<int J, bool BNRELU>
__global__ __launch_bounds__(256, 2)
void gemm_mfma(const ushort* __restrict__ h, const float* __restrict__ W,
               const float* __restrict__ ab, const float* __restrict__ dinv,
               ushort* __restrict__ outb) {
    constexpr int NT = (J + 15) / 16;   // 5 (J=75) or 4 (J=64)
    constexpr int JP = NT * 16;         // 80 or 64
    constexpr int OS = JP;
    __shared__ ushort Wl[JP * KP];
    __shared__ ushort Hl[64 * KP];
    int tl = threadIdx.x;
    int rbase = blockIdx.x * 64;
    for (int idx = tl; idx < 96 * JP; idx += 256) {
        int k = idx / JP, n = idx % JP;
        float v = (k < HID && n < J) ? W[k * J + n] : 0.0f;
        Wl[n * KP + k] = f2bf(v);
    }
    // stage H tile: 64 rows x 20 uint2 chunks (4 bf16 each)
    for (int idx = tl; idx < 64 * 20; idx += 256) {
        int r = idx / 20, c = idx % 20;
        int row = rbase + r; if (row >= NN) row = NN - 1;
        uint2 raw = reinterpret_cast<const uint2*>(h + (size_t)row * SP)[c];
        ushort4 u;
        if (BNRELU) {
            float v0 = bf_lo(raw.x), v1 = bf_hi(raw.x), v2 = bf_lo(raw.y), v3 = bf_hi(raw.y);
            float4 a4 = reinterpret_cast<const float4*>(ab)[c];
            float4 c4 = reinterpret_cast<const float4*>(ab + SP)[c];
            u.x = f2bf(fmaxf(fmaf(v0, a4.x, c4.x), 0.f));
            u.y = f2bf(fmaxf(fmaf(v1, a4.y, c4.y), 0.f));
            u.z = f2bf(fmaxf(fmaf(v2, a4.z, c4.z), 0.f));
            u.w = f2bf(fmaxf(fmaf(v3, a4.w, c4.w), 0.f));
        } else {
            u.x = (ushort)(raw.x & 0xFFFF); u.y = (ushort)(raw.x >> 16);
            u.z = (ushort)(raw.y & 0xFFFF); u.w = (ushort)(raw.y >> 16);
        }
        *reinterpret_cast<ushort4*>(&Hl[r * KP + c * 4]) = u;
    }
    for (int idx = tl; idx < 64 * 16; idx += 256) {
        int r = idx / 16, k = 80 + (idx % 16);
        Hl[r * KP + k] = 0;
    }
    __syncthreads();
    int w = tl >> 6;
    int l = tl & 63;
    int cq = l & 15;
    int q  = l >> 4;
    f32x4 acc[NT] = {};
    #pragma unroll
    for (int ks = 0; ks < 3; ++ks) {
        int k0 = ks * 32 + q * 8;
        bf16x8 a = *reinterpret_cast<const bf16x8*>(&Hl[(w * 16 + cq) * KP + k0]);
        #pragma unroll
        for (int t = 0; t < NT; ++t) {
            bf16x8 b = *reinterpret_cast<const bf16x8*>(&Wl[(t * 16 + cq) * KP + k0]);
            acc[t] = __builtin_amdgcn_mfma_f32_16x16x32_bf16(a, b, acc[t], 0, 0, 0);
        }
    }
    int r0 = rbase + w * 16 + q * 4;
    #pragma unroll
    for (int r = 0; r < 4; ++r) {
        int grow = r0 + r;
        if (grow < NN) {
            float d = dinv[grow];
            ushort* orow = outb + (size_t)grow * OS;
            #pragma unroll
            for (int t = 0; t < NT; ++t)
                orow[t * 16 + cq] = f2bf(acc[t][r] * d);
        }
    }
}

// Fused final GEMM: J=128 (W_mu || W_ls), outb stride 128.
__global__ __launch_bounds__(256, 2)
void gemm_mfma_dual(const ushort* __restrict__ h, const float* __restrict__ Wmu,
                    const float* __restrict__ Wls, const float* __restrict__ ab,
                    const float* __restrict__ dinv, ushort* __restrict__ outb) {
    constexpr int NT = 8;
    constexpr int JP = 128;
    __shared__ ushort Wl[JP * KP];   // 26.6 KB
    __shared__ ushort Hl[64 * KP];   // 13.3 KB
    int tl = threadIdx.x;
    int rbase = blockIdx.x * 64;
    for (int idx = tl; idx < 96 * JP; idx += 256) {
        int k = idx / JP, n = idx % JP;
        float v = 0.f;
        if (k < HID) v = (n < 64) ? Wmu[k * 64 + n] : Wls[k * 64 + (n - 64)];
        Wl[n * KP + k] = f2bf(v);
    }
    for (int idx = tl; idx < 64 * 20; idx += 256) {
        int r = idx / 20, c = idx % 20;
        int row = rbase + r; if (row >= NN) row = NN - 1;
        uint2 raw = reinterpret_cast<const uint2*>(h + (size_t)row * SP)[c];
        float v0 = bf_lo(raw.x), v1 = bf_hi(raw.x), v2 = bf_lo(raw.y), v3 = bf_hi(raw.y);
        float4 a4 = reinterpret_cast<const float4*>(ab)[c];
        float4 c4 = reinterpret_cast<const float4*>(ab + SP)[c];
        ushort4 u;
        u.x = f2bf(fmaxf(fmaf(v0, a4.x, c4.x), 0.f));
        u.y = f2bf(fmaxf(fmaf(v1, a4.y, c4.y), 0.f));
        u.z = f2bf(fmaxf(fmaf(v2, a4.z, c4.z), 0.f));
        u.w = f2bf(fmaxf(fmaf(v3, a4.w, c4.w), 0.f));
        *reinterpret_cast<ushort4*>(&Hl[r * KP + c * 4]) = u;
    }
    for (int idx = tl; idx < 64 * 16; idx += 256) {
        int r = idx / 16, k = 80 + (idx % 16);
        Hl[r * KP + k] = 0;
    }
    __syncthreads();
    int w = tl >> 6;
    int l = tl & 63;
    int cq = l & 15;
    int q  = l >> 4;
    f32x4 acc[NT] = {};
    #pragma unroll
    for (int ks = 0; ks < 3; ++ks) {
        int k0 = ks * 32 + q * 8;
        bf16x8 a = *reinterpret_cast<const bf16x8*>(&Hl[(w * 16 + cq) * KP + k0]);
        #pragma unroll
        for (int t = 0; t < NT; ++t) {
            bf16x8 b = *reinterpret_cast<const bf16x8*>(&Wl[(t * 16 + cq) * KP + k0]);
            acc[t] = __builtin_amdgcn_mfma_f32_16x16x32_bf16(a, b, acc[t], 0, 0, 0);
        }
    }
    int r0 = rbase + w * 16 + q * 4;
    #pragma unroll
    for (int r = 0; r < 4; ++r) {
        int grow = r0 + r;
        if (grow < NN) {
            float d = dinv[grow];
            ushort* orow = outb + (size_t)grow * 128;
            #pragma unroll
            for (int t = 0; t < NT; ++t)
                orow[t * 16 + cq] = f2bf(acc[t][r] * d);
        }
    }
}

// ---------------- CSR gather (bf16 uint2 loads, no barriers, no atomics) ----------------
#define ACCUM(W) \
    a0 += bf_lo(W.x); a1 += bf_hi(W.x); a2 += bf_lo(W.y); a3 += bf_hi(W.y);

// 20 lanes per row, 8B per lane, unroll-4. bf16 output (agg).
__global__ void gather75(const int* __restrict__ row_ptr, const int* __restrict__ col,
                         const uint2* __restrict__ hWb, const float* __restrict__ dinv,
                         ushort* __restrict__ agg) {
    int t = blockIdx.x * 256 + threadIdx.x;
    if (t >= NN * 20) return;
    int n = t / 20, c = t % 20;
    int beg = row_ptr[n], end = row_ptr[n + 1];
    uint2 v = hWb[(size_t)n * 20 + c];     // self term (pre-scaled by dinv[src])
    float a0 = bf_lo(v.x), a1 = bf_hi(v.x), a2 = bf_lo(v.y), a3 = bf_hi(v.y);
    int e = beg;
    for (; e + 3 < end; e += 4) {
        int s0 = col[e], s1 = col[e + 1], s2 = col[e + 2], s3 = col[e + 3];
        uint2 w0 = hWb[(size_t)s0 * 20 + c];
        uint2 w1 = hWb[(size_t)s1 * 20 + c];
        uint2 w2 = hWb[(size_t)s2 * 20 + c];
        uint2 w3 = hWb[(size_t)s3 * 20 + c];
        ACCUM(w0) ACCUM(w1) ACCUM(w2) ACCUM(w3)
    }
    for (; e < end; ++e) {
        uint2 w0 = hWb[(size_t)col[e] * 20 + c];
        ACCUM(w0)
    }
    float d = dinv[n];
    ushort4 o;
    o.x = f2bf(a0 * d); o.y = f2bf(a1 * d); o.z = f2bf(a2 * d); o.w = f2bf(a3 * d);
    reinterpret_cast<ushort4*>(agg)[(size_t)n * 20 + c] = o;
}

// Fused mu+logstd gather: 32 lanes per row over the 128-wide dual hW. fp32 out.
__global__ void gather128(const int* __restrict__ row_ptr, const int* __restrict__ col,
                          const uint2* __restrict__ hWb, const float* __restrict__ dinv,
                          const float* __restrict__ b_mu, const float* __restrict__ b_ls,
                          float* __restrict__ out_mu, float* __restrict__ out_ls) {
    int t = blockIdx.x * 256 + threadIdx.x;
    int n = t >> 5;
    int c = t & 31;
    int beg = row_ptr[n], end = row_ptr[n + 1];
    uint2 v = hWb[(size_t)n * 32 + c];
    float a0 = bf_lo(v.x), a1 = bf_hi(v.x), a2 = bf_lo(v.y), a3 = bf_hi(v.y);
    int e = beg;
    for (; e + 3 < end; e += 4) {
        int s0 = col[e], s1 = col[e + 1], s2 = col[e + 2], s3 = col[e + 3];
        uint2 w0 = hWb[(size_t)s0 * 32 + c];
        uint2 w1 = hWb[(size_t)s1 * 32 + c];
        uint2 w2 = hWb[(size_t)s2 * 32 + c];
        uint2 w3 = hWb[(size_t)s3 * 32 + c];
        ACCUM(w0) ACCUM(w1) ACCUM(w2) ACCUM(w3)
    }
    for (; e < end; ++e) {
        uint2 w0 = hWb[(size_t)col[e] * 32 + c];
        ACCUM(w0)
    }
    float d = dinv[n];
    const float* bp = (c < 16) ? (b_mu + c * 4) : (b_ls + (c - 16) * 4);
    float* op = (c < 16) ? (out_mu + (size_t)n * 64 + c * 4)
                         : (out_ls + (size_t)n * 64 + (c - 16) * 4);
    float4 b = *reinterpret_cast<const float4*>(bp);
    *reinterpret_cast<float4*>(op) =
        make_float4(fmaf(a0, d, b.x), fmaf(a1, d, b.y), fmaf(a2, d, b.z), fmaf(a3, d, b.w));
}

// ---------------- BN stats: column sum & sumsq over bf16 agg ----------------
__global__ void stats_kernel(const ushort* __restrict__ agg, float* __restrict__ stats) {
    __shared__ float ssum[SP], ssq[SP];
    int tl = threadIdx.x;
    if (tl < SP) { ssum[tl] = 0.f; ssq[tl] = 0.f; }
    __syncthreads();
    int gtid = blockIdx.x * blockDim.x + tl;
    int T = gridDim.x * blockDim.x;          // divisible by 20
    int c = gtid % 20;
    int r = gtid / 20;
    int rstep = T / 20;
    float s0 = 0.f, s1 = 0.f, s2 = 0.f, s3 = 0.f;
    float q0 = 0.f, q1 = 0.f, q2 = 0.f, q3 = 0.f;
    const uint2* a2 = reinterpret_cast<const uint2*>(agg);
    for (; r < NN; r += rstep) {
        uint2 v = a2[r * 20 + c];
        float v0 = bf_lo(v.x), v1 = bf_hi(v.x), v2 = bf_lo(v.y), v3 = bf_hi(v.y);
        s0 += v0; s1 += v1; s2 += v2; s3 += v3;
        q0 += v0 * v0; q1 += v1 * v1; q2 += v2 * v2; q3 += v3 * v3;
    }
    int fb = c * 4;
    atomicAdd(&ssum[fb + 0], s0); atomicAdd(&ssq[fb + 0], q0);
    atomicAdd(&ssum[fb + 1], s1); atomicAdd(&ssq[fb + 1], q1);
    atomicAdd(&ssum[fb + 2], s2); atomicAdd(&ssq[fb + 2], q2);
    atomicAdd(&ssum[fb + 3], s3); atomicAdd(&ssq[fb + 3], q3);
    __syncthreads();
    if (tl < SP) {
        atomicAdd(&stats[tl], ssum[tl]);
        atomicAdd(&stats[SP + tl], ssq[tl]);
    }
}

__global__ void bn_finalize(const float* __restrict__ stats, const float* __restrict__ gamma,
                            const float* __restrict__ beta, float* __restrict__ ab) {
    int f = threadIdx.x;
    if (f >= SP) return;
    float a = 0.f, cc = 0.f;
    if (f < HID) {
        float mu = stats[f] * (1.0f / NN);
        float var = stats[SP + f] * (1.0f / NN) - mu * mu;
        a = gamma[f] * rsqrtf(var + BN_EPS);
        cc = beta[f] - mu * a;
    }
    ab[f] = a;
    ab[SP + f] = cc;
}

// ---------------- host ----------------
extern "C" void kernel_launch(void* const* d_in, const int* in_sizes, int n_in,
                              void* d_out, int out_size, void* d_ws, size_t ws_size,
                              hipStream_t stream) {
    const int*   x      = (const int*)d_in[0];
    const int*   ei     = (const int*)d_in[1];
    const float* emb    = (const float*)d_in[2];
    const float* Ws     = (const float*)d_in[3];
    const float* gammas = (const float*)d_in[5];
    const float* betas  = (const float*)d_in[6];
    const float* W_mu   = (const float*)d_in[7];
    const float* b_mu   = (const float*)d_in[8];
    const float* W_ls   = (const float*)d_in[9];
    const float* b_ls   = (const float*)d_in[10];
    float* out = (float*)d_out;

    const int E = in_sizes[1] / 2;
    const int* src = ei;
    const int* dst = ei + E;

    char* ws = (char*)d_ws;
    // zero-region [0, 803072): hist, cnt, stats4 — one memset
    int*    hist    = (int*)   (ws + 0);            // 400,000 B
    int*    cnt     = (int*)   (ws + 400000);       // 400,000 B
    float*  stats4  = (float*) (ws + 800000);       // 4 layers x 160 floats = 2560 B
    // (zero region ends at 802,560; round to 803,072)
    float*  dinv    = (float*) (ws + 803072);       // 400,000 B
    float*  ab      = (float*) (ws + 1203072);      // 640 B
    int*    bsum    = (int*)   (ws + 1203712);      // 512 B
    int*    row_ptr = (int*)   (ws + 1204224);      // 400,128 B
    int*    col     = (int*)   (ws + 1604352);      // 4,000,000 B
    ushort* hA      = (ushort*)(ws + 5604352);      // NN*80 bf16 = 16,000,000 B
    ushort* hBb     = (ushort*)(ws + 21604352);     // NN*128 bf16 max = 25,600,000 B

    // --- one upfront memset for hist + cnt + stats slices ---
    hipMemsetAsync(ws, 0, 803072, stream);

    // --- CSR build ---
    hist_kernel<<<(E + 255) / 256, 256, 0, stream>>>(dst, hist, E);
    dinv_kernel<<<(NN + 255) / 256, 256, 0, stream>>>(hist, dinv, NN);
    scan_pass1<<<SCAN_NBLK, 256, 0, stream>>>(hist, bsum);
    scan_pass2<<<1, 64, 0, stream>>>(bsum, row_ptr, SCAN_NBLK);
    scan_pass3<<<SCAN_NBLK, 256, 0, stream>>>(hist, bsum, row_ptr);
    csr_fill<<<(E + 255) / 256, 256, 0, stream>>>(src, dst, row_ptr, cnt, col, E);

    // --- h0 = emb[x] (bf16) ---
    embed_kernel<<<(NN * SP + 255) / 256, 256, 0, stream>>>(x, emb, hA);

    // --- 4 GCN+BN+ReLU layers ---
    for (int layer = 0; layer < 4; ++layer) {
        const float* W = Ws + (size_t)layer * HID * HID;
        float* stats = stats4 + layer * 160;
        if (layer == 0)
            gemm_mfma<HID, false><<<(NN + 63) / 64, 256, 0, stream>>>(hA, W, ab, dinv, hBb);
        else
            gemm_mfma<HID, true><<<(NN + 63) / 64, 256, 0, stream>>>(hA, W, ab, dinv, hBb);
        gather75<<<(NN * 20 + 255) / 256, 256, 0, stream>>>(row_ptr, col,
                                                            (const uint2*)hBb, dinv, hA);
        stats_kernel<<<640, 256, 0, stream>>>(hA, stats);
        bn_finalize<<<1, 128, 0, stream>>>(stats, gammas + layer * HID, betas + layer * HID, ab);
    }

    // --- fused mu + logstd ---
    float* out2 = out + (size_t)NN * OUTF;
    gemm_mfma_dual<<<(NN + 63) / 64, 256, 0, stream>>>(hA, W_mu, W_ls, ab, dinv, hBb);
    gather128<<<(NN * 32) / 256, 256, 0, stream>>>(row_ptr, col, (const uint2*)hBb,
                                                   dinv, b_mu, b_ls, out, out2);
}

// Round 12
// 566.013 us; speedup vs baseline: 2.1705x; 1.0176x over previous
//
#include <hip/hip_runtime.h>

#define NN 100000      // N_NODES
#define NE 1000000     // N_EDGES
#define HID 75
#define SP 80          // padded feature stride (bf16 h buffers)
#define OUTF 64
#define BN_EPS 1e-5f
#define KP 104         // LDS k-stride in bf16 (96 used; 16B-aligned, ~2-way banks)

#define SCAN_ELEMS 1024
#define SCAN_NBLK ((NN + SCAN_ELEMS - 1) / SCAN_ELEMS)   // 98

typedef short bf16x8 __attribute__((ext_vector_type(8)));
typedef float f32x4  __attribute__((ext_vector_type(4)));

// bf16 helpers
__device__ __forceinline__ ushort f2bf(float f) {
    unsigned u = __float_as_uint(f);
    u += 0x7FFF + ((u >> 16) & 1);          // round-to-nearest-even
    return (ushort)(u >> 16);
}
__device__ __forceinline__ float bf_lo(unsigned u) { return __uint_as_float(u << 16); }
__device__ __forceinline__ float bf_hi(unsigned u) { return __uint_as_float(u & 0xFFFF0000u); }

// ---------------- CSR build ----------------
__global__ void hist_kernel(const int* __restrict__ dst, int* __restrict__ hist, int E) {
    int e = blockIdx.x * blockDim.x + threadIdx.x;
    if (e < E) atomicAdd(&hist[dst[e]], 1);
}

// scan pass1 + dinv fused (reads each hist[i] exactly once anyway)
__global__ void scan_pass1(const int* __restrict__ hist, int* __restrict__ bsum,
                           float* __restrict__ dinv) {
    __shared__ int sdata[256];
    int base = blockIdx.x * SCAN_ELEMS;
    int t = threadIdx.x;
    int s = 0;
    #pragma unroll
    for (int k = 0; k < 4; ++k) {
        int i = base + t * 4 + k;
        if (i < NN) {
            int hv = hist[i];
            s += hv;
            dinv[i] = rsqrtf((float)hv + 1.0f);   // +1 self-loop
        }
    }
    sdata[t] = s;
    __syncthreads();
    for (int off = 128; off > 0; off >>= 1) {
        if (t < off) sdata[t] += sdata[t + off];
        __syncthreads();
    }
    if (t == 0) bsum[blockIdx.x] = sdata[0];
}

__global__ void scan_pass2(int* __restrict__ bsum, int* __restrict__ row_ptr, int nblk) {
    if (threadIdx.x == 0) {
        int acc = 0;
        for (int i = 0; i < nblk; ++i) { int v = bsum[i]; bsum[i] = acc; acc += v; }
        row_ptr[NN] = acc;
    }
}

__global__ void scan_pass3(const int* __restrict__ hist, const int* __restrict__ bsum,
                           int* __restrict__ row_ptr) {
    __shared__ int sdata[256];
    int base = blockIdx.x * SCAN_ELEMS;
    int t = threadIdx.x;
    int v[4];
    int s = 0;
    #pragma unroll
    for (int k = 0; k < 4; ++k) {
        int i = base + t * 4 + k;
        v[k] = (i < NN) ? hist[i] : 0;
        s += v[k];
    }
    sdata[t] = s;
    __syncthreads();
    for (int off = 1; off < 256; off <<= 1) {
        int x = (t >= off) ? sdata[t - off] : 0;
        __syncthreads();
        sdata[t] += x;
        __syncthreads();
    }
    int pre = bsum[blockIdx.x] + sdata[t] - s;
    #pragma unroll
    for (int k = 0; k < 4; ++k) {
        int i = base + t * 4 + k;
        if (i < NN) { row_ptr[i] = pre; pre += v[k]; }
    }
}

__global__ void csr_fill(const int* __restrict__ src, const int* __restrict__ dst,
                         const int* __restrict__ row_ptr, int* __restrict__ cnt,
                         int* __restrict__ col, int E) {
    int e = blockIdx.x * blockDim.x + threadIdx.x;
    if (e >= E) return;
    int d = dst[e];
    int slot = row_ptr[d] + atomicAdd(&cnt[d], 1);
    col[slot] = src[e];
}

// ---------------- embedding gather (bf16 out) ----------------
__global__ void embed_kernel(const int* __restrict__ x, const float* __restrict__ emb,
                             ushort* __restrict__ h) {
    int t = blockIdx.x * blockDim.x + threadIdx.x;
    if (t >= NN * SP) return;
    int node = t / SP, f = t % SP;
    h[t] = (f < HID) ? f2bf(emb[x[node] * HID + f]) : (ushort)0;
}

// ---------------- MFMA GEMM: outb[n] = bf16( dinv[n] * (BNReLU(h[n]) @ W) ) ----------------
// BN finalize fused: block computes affine (a,c) from stats+gamma+beta into LDS.
template<int J, bool BNRELU>
__global__ __launch_bounds__(256, 2)
void gemm_mfma(const ushort* __restrict__ h, const float* __restrict__ W,
               const float* __restrict__ stats, const float* __restrict__ gamma,
               const float* __restrict__ beta, const float* __restrict__ dinv,
               ushort* __restrict__ outb) {
    constexpr int NT = (J + 15) / 16;   // 5 (J=75) or 4 (J=64)
    constexpr int JP = NT * 16;         // 80 or 64
    constexpr int OS = JP;
    __shared__ ushort Wl[JP * KP];
    __shared__ ushort Hl[64 * KP];
    __shared__ __align__(16) float sA[SP];
    __shared__ __align__(16) float sC[SP];
    int tl = threadIdx.x;
    int rbase = blockIdx.x * 64;
    if (BNRELU) {
        if (tl < SP) {
            float a = 0.f, cc = 0.f;
            if (tl < HID) {
                float mu = stats[tl] * (1.0f / NN);
                float var = stats[SP + tl] * (1.0f / NN) - mu * mu;
                a = gamma[tl] * rsqrtf(var + BN_EPS);
                cc = beta[tl] - mu * a;
            }
            sA[tl] = a;
            sC[tl] = cc;
        }
        __syncthreads();
    }
    for (int idx = tl; idx < 96 * JP; idx += 256) {
        int k = idx / JP, n = idx % JP;
        float v = (k < HID && n < J) ? W[k * J + n] : 0.0f;
        Wl[n * KP + k] = f2bf(v);
    }
    // stage H tile: 64 rows x 20 uint2 chunks (4 bf16 each)
    for (int idx = tl; idx < 64 * 20; idx += 256) {
        int r = idx / 20, c = idx % 20;
        int row = rbase + r; if (row >= NN) row = NN - 1;
        uint2 raw = reinterpret_cast<const uint2*>(h + (size_t)row * SP)[c];
        ushort4 u;
        if (BNRELU) {
            float v0 = bf_lo(raw.x), v1 = bf_hi(raw.x), v2 = bf_lo(raw.y), v3 = bf_hi(raw.y);
            float4 a4 = *reinterpret_cast<const float4*>(sA + c * 4);
            float4 c4 = *reinterpret_cast<const float4*>(sC + c * 4);
            u.x = f2bf(fmaxf(fmaf(v0, a4.x, c4.x), 0.f));
            u.y = f2bf(fmaxf(fmaf(v1, a4.y, c4.y), 0.f));
            u.z = f2bf(fmaxf(fmaf(v2, a4.z, c4.z), 0.f));
            u.w = f2bf(fmaxf(fmaf(v3, a4.w, c4.w), 0.f));
        } else {
            u.x = (ushort)(raw.x & 0xFFFF); u.y = (ushort)(raw.x >> 16);
            u.z = (ushort)(raw.y & 0xFFFF); u.w = (ushort)(raw.y >> 16);
        }
        *reinterpret_cast<ushort4*>(&Hl[r * KP + c * 4]) = u;
    }
    for (int idx = tl; idx < 64 * 16; idx += 256) {
        int r = idx / 16, k = 80 + (idx % 16);
        Hl[r * KP + k] = 0;
    }
    __syncthreads();
    int w = tl >> 6;
    int l = tl & 63;
    int cq = l & 15;
    int q  = l >> 4;
    f32x4 acc[NT] = {};
    #pragma unroll
    for (int ks = 0; ks < 3; ++ks) {
        int k0 = ks * 32 + q * 8;
        bf16x8 a = *reinterpret_cast<const bf16x8*>(&Hl[(w * 16 + cq) * KP + k0]);
        #pragma unroll
        for (int t = 0; t < NT; ++t) {
            bf16x8 b = *reinterpret_cast<const bf16x8*>(&Wl[(t * 16 + cq) * KP + k0]);
            acc[t] = __builtin_amdgcn_mfma_f32_16x16x32_bf16(a, b, acc[t], 0, 0, 0);
        }
    }
    int r0 = rbase + w * 16 + q * 4;
    #pragma unroll
    for (int r = 0; r < 4; ++r) {
        int grow = r0 + r;
        if (grow < NN) {
            float d = dinv[grow];
            ushort* orow = outb + (size_t)grow * OS;
            #pragma unroll
            for (int t = 0; t < NT; ++t)
                orow[t * 16 + cq] = f2bf(acc[t][r] * d);
        }
    }
}

// Fused final GEMM: J=128 (W_mu || W_ls), outb stride 128. BN finalize fused.
__global__ __launch_bounds__(256, 2)
void gemm_mfma_dual(const ushort* __restrict__ h, const float* __restrict__ Wmu,
                    const float* __restrict__ Wls, const float* __restrict__ stats,
                    const float* __restrict__ gamma, const float* __restrict__ beta,
                    const float* __restrict__ dinv, ushort* __restrict__ outb) {
    constexpr int NT = 8;
    constexpr int JP = 128;
    __shared__ ushort Wl[JP * KP];   // 26.6 KB
    __shared__ ushort Hl[64 * KP];   // 13.3 KB
    __shared__ __align__(16) float sA[SP];
    __shared__ __align__(16) float sC[SP];
    int tl = threadIdx.x;
    int rbase = blockIdx.x * 64;
    if (tl < SP) {
        float a = 0.f, cc = 0.f;
        if (tl < HID) {
            float mu = stats[tl] * (1.0f / NN);
            float var = stats[SP + tl] * (1.0f / NN) - mu * mu;
            a = gamma[tl] * rsqrtf(var + BN_EPS);
            cc = beta[tl] - mu * a;
        }
        sA[tl] = a;
        sC[tl] = cc;
    }
    __syncthreads();
    for (int idx = tl; idx < 96 * JP; idx += 256) {
        int k = idx / JP, n = idx % JP;
        float v = 0.f;
        if (k < HID) v = (n < 64) ? Wmu[k * 64 + n] : Wls[k * 64 + (n - 64)];
        Wl[n * KP + k] = f2bf(v);
    }
    for (int idx = tl; idx < 64 * 20; idx += 256) {
        int r = idx / 20, c = idx % 20;
        int row = rbase + r; if (row >= NN) row = NN - 1;
        uint2 raw = reinterpret_cast<const uint2*>(h + (size_t)row * SP)[c];
        float v0 = bf_lo(raw.x), v1 = bf_hi(raw.x), v2 = bf_lo(raw.y), v3 = bf_hi(raw.y);
        float4 a4 = *reinterpret_cast<const float4*>(sA + c * 4);
        float4 c4 = *reinterpret_cast<const float4*>(sC + c * 4);
        ushort4 u;
        u.x = f2bf(fmaxf(fmaf(v0, a4.x, c4.x), 0.f));
        u.y = f2bf(fmaxf(fmaf(v1, a4.y, c4.y), 0.f));
        u.z = f2bf(fmaxf(fmaf(v2, a4.z, c4.z), 0.f));
        u.w = f2bf(fmaxf(fmaf(v3, a4.w, c4.w), 0.f));
        *reinterpret_cast<ushort4*>(&Hl[r * KP + c * 4]) = u;
    }
    for (int idx = tl; idx < 64 * 16; idx += 256) {
        int r = idx / 16, k = 80 + (idx % 16);
        Hl[r * KP + k] = 0;
    }
    __syncthreads();
    int w = tl >> 6;
    int l = tl & 63;
    int cq = l & 15;
    int q  = l >> 4;
    f32x4 acc[NT] = {};
    #pragma unroll
    for (int ks = 0; ks < 3; ++ks) {
        int k0 = ks * 32 + q * 8;
        bf16x8 a = *reinterpret_cast<const bf16x8*>(&Hl[(w * 16 + cq) * KP + k0]);
        #pragma unroll
        for (int t = 0; t < NT; ++t) {
            bf16x8 b = *reinterpret_cast<const bf16x8*>(&Wl[(t * 16 + cq) * KP + k0]);
            acc[t] = __builtin_amdgcn_mfma_f32_16x16x32_bf16(a, b, acc[t], 0, 0, 0);
        }
    }
    int r0 = rbase + w * 16 + q * 4;
    #pragma unroll
    for (int r = 0; r < 4; ++r) {
        int grow = r0 + r;
        if (grow < NN) {
            float d = dinv[grow];
            ushort* orow = outb + (size_t)grow * 128;
            #pragma unroll
            for (int t = 0; t < NT; ++t)
                orow[t * 16 + cq] = f2bf(acc[t][r] * d);
        }
    }
}

// ---------------- CSR gather (bf16 uint2 loads, no barriers, no atomics) ----------------
#define ACCUM(W) \
    a0 += bf_lo(W.x); a1 += bf_hi(W.x); a2 += bf_lo(W.y); a3 += bf_hi(W.y);

// 20 lanes per row, 8B per lane, unroll-4. bf16 output (agg).
__global__ void gather75(const int* __restrict__ row_ptr, const int* __restrict__ col,
                         const uint2* __restrict__ hWb, const float* __restrict__ dinv,
                         ushort* __restrict__ agg) {
    int t = blockIdx.x * 256 + threadIdx.x;
    if (t >= NN * 20) return;
    int n = t / 20, c = t % 20;
    int beg = row_ptr[n], end = row_ptr[n + 1];
    uint2 v = hWb[(size_t)n * 20 + c];     // self term (pre-scaled by dinv[src])
    float a0 = bf_lo(v.x), a1 = bf_hi(v.x), a2 = bf_lo(v.y), a3 = bf_hi(v.y);
    int e = beg;
    for (; e + 3 < end; e += 4) {
        int s0 = col[e], s1 = col[e + 1], s2 = col[e + 2], s3 = col[e + 3];
        uint2 w0 = hWb[(size_t)s0 * 20 + c];
        uint2 w1 = hWb[(size_t)s1 * 20 + c];
        uint2 w2 = hWb[(size_t)s2 * 20 + c];
        uint2 w3 = hWb[(size_t)s3 * 20 + c];
        ACCUM(w0) ACCUM(w1) ACCUM(w2) ACCUM(w3)
    }
    for (; e < end; ++e) {
        uint2 w0 = hWb[(size_t)col[e] * 20 + c];
        ACCUM(w0)
    }
    float d = dinv[n];
    ushort4 o;
    o.x = f2bf(a0 * d); o.y = f2bf(a1 * d); o.z = f2bf(a2 * d); o.w = f2bf(a3 * d);
    reinterpret_cast<ushort4*>(agg)[(size_t)n * 20 + c] = o;
}

// Fused mu+logstd gather: 32 lanes per row over the 128-wide dual hW. fp32 out.
__global__ void gather128(const int* __restrict__ row_ptr, const int* __restrict__ col,
                          const uint2* __restrict__ hWb, const float* __restrict__ dinv,
                          const float* __restrict__ b_mu, const float* __restrict__ b_ls,
                          float* __restrict__ out_mu, float* __restrict__ out_ls) {
    int t = blockIdx.x * 256 + threadIdx.x;
    int n = t >> 5;
    int c = t & 31;
    int beg = row_ptr[n], end = row_ptr[n + 1];
    uint2 v = hWb[(size_t)n * 32 + c];
    float a0 = bf_lo(v.x), a1 = bf_hi(v.x), a2 = bf_lo(v.y), a3 = bf_hi(v.y);
    int e = beg;
    for (; e + 3 < end; e += 4) {
        int s0 = col[e], s1 = col[e + 1], s2 = col[e + 2], s3 = col[e + 3];
        uint2 w0 = hWb[(size_t)s0 * 32 + c];
        uint2 w1 = hWb[(size_t)s1 * 32 + c];
        uint2 w2 = hWb[(size_t)s2 * 32 + c];
        uint2 w3 = hWb[(size_t)s3 * 32 + c];
        ACCUM(w0) ACCUM(w1) ACCUM(w2) ACCUM(w3)
    }
    for (; e < end; ++e) {
        uint2 w0 = hWb[(size_t)col[e] * 32 + c];
        ACCUM(w0)
    }
    float d = dinv[n];
    const float* bp = (c < 16) ? (b_mu + c * 4) : (b_ls + (c - 16) * 4);
    float* op = (c < 16) ? (out_mu + (size_t)n * 64 + c * 4)
                         : (out_ls + (size_t)n * 64 + (c - 16) * 4);
    float4 b = *reinterpret_cast<const float4*>(bp);
    *reinterpret_cast<float4*>(op) =
        make_float4(fmaf(a0, d, b.x), fmaf(a1, d, b.y), fmaf(a2, d, b.z), fmaf(a3, d, b.w));
}

// ---------------- BN stats: column sum & sumsq over bf16 agg ----------------
__global__ void stats_kernel(const ushort* __restrict__ agg, float* __restrict__ stats) {
    __shared__ float ssum[SP], ssq[SP];
    int tl = threadIdx.x;
    if (tl < SP) { ssum[tl] = 0.f; ssq[tl] = 0.f; }
    __syncthreads();
    int gtid = blockIdx.x * blockDim.x + tl;
    int T = gridDim.x * blockDim.x;          // divisible by 20
    int c = gtid % 20;
    int r = gtid / 20;
    int rstep = T / 20;
    float s0 = 0.f, s1 = 0.f, s2 = 0.f, s3 = 0.f;
    float q0 = 0.f, q1 = 0.f, q2 = 0.f, q3 = 0.f;
    const uint2* a2 = reinterpret_cast<const uint2*>(agg);
    for (; r < NN; r += rstep) {
        uint2 v = a2[r * 20 + c];
        float v0 = bf_lo(v.x), v1 = bf_hi(v.x), v2 = bf_lo(v.y), v3 = bf_hi(v.y);
        s0 += v0; s1 += v1; s2 += v2; s3 += v3;
        q0 += v0 * v0; q1 += v1 * v1; q2 += v2 * v2; q3 += v3 * v3;
    }
    int fb = c * 4;
    atomicAdd(&ssum[fb + 0], s0); atomicAdd(&ssq[fb + 0], q0);
    atomicAdd(&ssum[fb + 1], s1); atomicAdd(&ssq[fb + 1], q1);
    atomicAdd(&ssum[fb + 2], s2); atomicAdd(&ssq[fb + 2], q2);
    atomicAdd(&ssum[fb + 3], s3); atomicAdd(&ssq[fb + 3], q3);
    __syncthreads();
    if (tl < SP) {
        atomicAdd(&stats[tl], ssum[tl]);
        atomicAdd(&stats[SP + tl], ssq[tl]);
    }
}

// ---------------- host ----------------
extern "C" void kernel_launch(void* const* d_in, const int* in_sizes, int n_in,
                              void* d_out, int out_size, void* d_ws, size_t ws_size,
                              hipStream_t stream) {
    const int*   x      = (const int*)d_in[0];
    const int*   ei     = (const int*)d_in[1];
    const float* emb    = (const float*)d_in[2];
    const float* Ws     = (const float*)d_in[3];
    const float* gammas = (const float*)d_in[5];
    const float* betas  = (const float*)d_in[6];
    const float* W_mu   = (const float*)d_in[7];
    const float* b_mu   = (const float*)d_in[8];
    const float* W_ls   = (const float*)d_in[9];
    const float* b_ls   = (const float*)d_in[10];
    float* out = (float*)d_out;

    const int E = in_sizes[1] / 2;
    const int* src = ei;
    const int* dst = ei + E;

    char* ws = (char*)d_ws;
    // zero-region [0, 803072): hist, cnt, stats4 — one memset
    int*    hist    = (int*)   (ws + 0);            // 400,000 B
    int*    cnt     = (int*)   (ws + 400000);       // 400,000 B
    float*  stats4  = (float*) (ws + 800000);       // 4 layers x 160 floats = 2560 B
    float*  dinv    = (float*) (ws + 803072);       // 400,000 B
    int*    bsum    = (int*)   (ws + 1203712);      // 512 B
    int*    row_ptr = (int*)   (ws + 1204224);      // 400,128 B
    int*    col     = (int*)   (ws + 1604352);      // 4,000,000 B
    ushort* hA      = (ushort*)(ws + 5604352);      // NN*80 bf16 = 16,000,000 B
    ushort* hBb     = (ushort*)(ws + 21604352);     // NN*128 bf16 max = 25,600,000 B

    // --- one upfront memset for hist + cnt + stats slices ---
    hipMemsetAsync(ws, 0, 803072, stream);

    // --- CSR build (dinv fused into scan_pass1) ---
    hist_kernel<<<(E + 255) / 256, 256, 0, stream>>>(dst, hist, E);
    scan_pass1<<<SCAN_NBLK, 256, 0, stream>>>(hist, bsum, dinv);
    scan_pass2<<<1, 64, 0, stream>>>(bsum, row_ptr, SCAN_NBLK);
    scan_pass3<<<SCAN_NBLK, 256, 0, stream>>>(hist, bsum, row_ptr);
    csr_fill<<<(E + 255) / 256, 256, 0, stream>>>(src, dst, row_ptr, cnt, col, E);

    // --- h0 = emb[x] (bf16) ---
    embed_kernel<<<(NN * SP + 255) / 256, 256, 0, stream>>>(x, emb, hA);

    // --- 4 GCN+BN+ReLU layers (bn_finalize fused into gemm staging) ---
    for (int layer = 0; layer < 4; ++layer) {
        const float* W = Ws + (size_t)layer * HID * HID;
        if (layer == 0)
            gemm_mfma<HID, false><<<(NN + 63) / 64, 256, 0, stream>>>(
                hA, W, nullptr, nullptr, nullptr, dinv, hBb);
        else
            gemm_mfma<HID, true><<<(NN + 63) / 64, 256, 0, stream>>>(
                hA, W, stats4 + (layer - 1) * 160, gammas + (layer - 1) * HID,
                betas + (layer - 1) * HID, dinv, hBb);
        gather75<<<(NN * 20 + 255) / 256, 256, 0, stream>>>(row_ptr, col,
                                                            (const uint2*)hBb, dinv, hA);
        stats_kernel<<<640, 256, 0, stream>>>(hA, stats4 + layer * 160);
    }

    // --- fused mu + logstd (uses layer-3 stats) ---
    float* out2 = out + (size_t)NN * OUTF;
    gemm_mfma_dual<<<(NN + 63) / 64, 256, 0, stream>>>(
        hA, W_mu, W_ls, stats4 + 3 * 160, gammas + 3 * HID, betas + 3 * HID, dinv, hBb);
    gather128<<<(NN * 32) / 256, 256, 0, stream>>>(row_ptr, col, (const uint2*)hBb,
                                                   dinv, b_mu, b_ls, out, out2);
}